// Round 1
// baseline (274.657 us; speedup 1.0000x reference)
//
#include <hip/hip_runtime.h>
#include <math.h>

#define B_  1024
#define S_  50
#define E_  512
#define L_  1024
#define D_  10
#define NN  1023   // N_NODES
#define LN_EPS 1e-5f

// ---------------- Kernel A: embedding gather + mean + LayerNorm ----------------
// One block per batch row b. 256 threads, each owns columns t and t+256.
__global__ __launch_bounds__(256) void k_embed_ln(const int* __restrict__ ids,
                                                  const float* __restrict__ emb,
                                                  float* __restrict__ x) {
    const int b = blockIdx.x;
    const int t = threadIdx.x;
    float a0 = 0.f, a1 = 0.f;
    const int* idr = ids + b * S_;
    for (int s = 0; s < S_; ++s) {
        const float* row = emb + (long)idr[s] * E_;
        a0 += row[t];
        a1 += row[t + 256];
    }
    a0 *= (1.f / S_);
    a1 *= (1.f / S_);

    __shared__ float red[256];
    // mean
    red[t] = a0 + a1;
    __syncthreads();
    for (int off = 128; off > 0; off >>= 1) {
        if (t < off) red[t] += red[t + off];
        __syncthreads();
    }
    const float mean = red[0] * (1.f / E_);
    __syncthreads();
    // variance (two-pass, matches jnp.var semantics)
    const float d0 = a0 - mean, d1 = a1 - mean;
    red[t] = d0 * d0 + d1 * d1;
    __syncthreads();
    for (int off = 128; off > 0; off >>= 1) {
        if (t < off) red[t] += red[t + off];
        __syncthreads();
    }
    const float var = red[0] * (1.f / E_);
    const float inv = 1.f / sqrtf(var + LN_EPS);
    x[b * E_ + t]       = d0 * inv;
    x[b * E_ + t + 256] = d1 * inv;
}

// ---------------- Kernel B: f32 GEMM  C[1024,512] = A[1024,512] @ W[512,512] + bias ----------------
#define BM 64
#define BN 32
#define BK 32

__global__ __launch_bounds__(256) void k_gemm_hidden(const float* __restrict__ A,
                                                     const float* __restrict__ W,
                                                     const float* __restrict__ bias,
                                                     float* __restrict__ C) {
    __shared__ float As[BM][BK + 1];
    __shared__ float Ws[BK][BN + 1];
    const int tid = threadIdx.x;
    const int tx = tid & 15;   // 16 col-groups * TN=2 -> 32 cols
    const int ty = tid >> 4;   // 16 row-groups * TM=4 -> 64 rows
    const int row0 = blockIdx.x * BM;
    const int col0 = blockIdx.y * BN;
    float acc[4][2] = {};
    for (int kt = 0; kt < E_; kt += BK) {
        #pragma unroll
        for (int i = 0; i < 2; ++i) {
            const int idx = tid + i * 256;
            const int r  = idx >> 3;
            const int c4 = (idx & 7) << 2;
            const float4 v = *reinterpret_cast<const float4*>(&A[(row0 + r) * E_ + kt + c4]);
            As[r][c4+0] = v.x; As[r][c4+1] = v.y; As[r][c4+2] = v.z; As[r][c4+3] = v.w;
        }
        {
            const int r  = tid >> 3;
            const int c4 = (tid & 7) << 2;
            const float4 v = *reinterpret_cast<const float4*>(&W[(kt + r) * E_ + col0 + c4]);
            Ws[r][c4+0] = v.x; Ws[r][c4+1] = v.y; Ws[r][c4+2] = v.z; Ws[r][c4+3] = v.w;
        }
        __syncthreads();
        #pragma unroll
        for (int k = 0; k < BK; ++k) {
            const float a0 = As[ty*4+0][k], a1 = As[ty*4+1][k];
            const float a2 = As[ty*4+2][k], a3 = As[ty*4+3][k];
            const float w0 = Ws[k][tx*2+0], w1 = Ws[k][tx*2+1];
            acc[0][0] += a0*w0; acc[0][1] += a0*w1;
            acc[1][0] += a1*w0; acc[1][1] += a1*w1;
            acc[2][0] += a2*w0; acc[2][1] += a2*w1;
            acc[3][0] += a3*w0; acc[3][1] += a3*w1;
        }
        __syncthreads();
    }
    #pragma unroll
    for (int m = 0; m < 4; ++m) {
        const int r = row0 + ty*4 + m;
        #pragma unroll
        for (int n = 0; n < 2; ++n) {
            const int c = col0 + tx*2 + n;
            C[r * E_ + c] = acc[m][n] + bias[c];
        }
    }
}

// ---------------- Kernel C: s[b,n] = x[b,:] . (thW[n,:,1]-thW[n,:,0]) + (thb[n,1]-thb[n,0]) ----------------
__global__ __launch_bounds__(256) void k_theta_gemm(const float* __restrict__ X,
                                                    const float* __restrict__ thW,
                                                    const float* __restrict__ thb,
                                                    float* __restrict__ Sm) {
    __shared__ float As[BM][BK + 1];
    __shared__ float Ds[BN][BK + 1];   // dW[n_local][e_local]
    const int tid = threadIdx.x;
    const int tx = tid & 15;
    const int ty = tid >> 4;
    const int row0 = blockIdx.x * BM;
    const int n0   = blockIdx.y * BN;
    float acc[4][2] = {};
    for (int kt = 0; kt < E_; kt += BK) {
        #pragma unroll
        for (int i = 0; i < 2; ++i) {
            const int idx = tid + i * 256;
            const int r  = idx >> 3;
            const int c4 = (idx & 7) << 2;
            const float4 v = *reinterpret_cast<const float4*>(&X[(row0 + r) * E_ + kt + c4]);
            As[r][c4+0] = v.x; As[r][c4+1] = v.y; As[r][c4+2] = v.z; As[r][c4+3] = v.w;
        }
        #pragma unroll
        for (int j = 0; j < 4; ++j) {
            const int idx = tid + j * 256;
            const int nl = idx >> 5;
            const int el = idx & 31;
            const int n  = n0 + nl;
            float dv = 0.f;
            if (n < NN) {
                const float2 v = *reinterpret_cast<const float2*>(&thW[((long)n * E_ + kt + el) * 2]);
                dv = v.y - v.x;
            }
            Ds[nl][el] = dv;
        }
        __syncthreads();
        #pragma unroll
        for (int k = 0; k < BK; ++k) {
            const float a0 = As[ty*4+0][k], a1 = As[ty*4+1][k];
            const float a2 = As[ty*4+2][k], a3 = As[ty*4+3][k];
            const float w0 = Ds[tx*2+0][k], w1 = Ds[tx*2+1][k];
            acc[0][0] += a0*w0; acc[0][1] += a0*w1;
            acc[1][0] += a1*w0; acc[1][1] += a1*w1;
            acc[2][0] += a2*w0; acc[2][1] += a2*w1;
            acc[3][0] += a3*w0; acc[3][1] += a3*w1;
        }
        __syncthreads();
    }
    #pragma unroll
    for (int m = 0; m < 4; ++m) {
        const int r = row0 + ty*4 + m;
        #pragma unroll
        for (int n = 0; n < 2; ++n) {
            const int c = n0 + tx*2 + n;
            if (c < NN) {
                Sm[(long)r * NN + c] = acc[m][n] + (thb[c*2+1] - thb[c*2+0]);
            }
        }
    }
}

// ---------------- Kernel D: per-leaf product of path sigmoids ----------------
__global__ __launch_bounds__(256) void k_leaf(const float* __restrict__ Sm,
                                              float* __restrict__ out) {
    const int idx = blockIdx.x * 256 + threadIdx.x;
    const int b = idx >> 10;         // / L_
    const int l = idx & (L_ - 1);
    const float* srow = Sm + (long)b * NN;
    float prod = 1.f;
    #pragma unroll
    for (int t = 0; t < D_; ++t) {
        const int node = (1 << t) - 1 + (l >> (D_ - t));
        const int bit  = (l >> (D_ - 1 - t)) & 1;
        float z = srow[node];
        z = bit ? z : -z;
        prod *= 1.f / (1.f + expf(-z));
    }
    out[idx] = prod;
}

extern "C" void kernel_launch(void* const* d_in, const int* in_sizes, int n_in,
                              void* d_out, int out_size, void* d_ws, size_t ws_size,
                              hipStream_t stream) {
    const int*   ids = (const int*)d_in[0];
    const float* emb = (const float*)d_in[1];
    const float* Wh  = (const float*)d_in[2];
    const float* bh  = (const float*)d_in[3];
    const float* thW = (const float*)d_in[4];
    const float* thb = (const float*)d_in[5];
    float* out = (float*)d_out;

    char* ws = (char*)d_ws;
    float* xa = (float*)(ws);                      // 1024*512*4 = 2 MB
    float* xb = (float*)(ws + (2u << 20));         // 2 MB
    float* sm = (float*)(ws + (4u << 20));         // 1024*1023*4 ≈ 4.19 MB

    // 1) embedding mean + LN
    k_embed_ln<<<B_, 256, 0, stream>>>(ids, emb, xa);

    // 2) ten hidden layers, ping-pong
    const float* in = xa;
    float* outx = xb;
    for (int i = 0; i < 10; ++i) {
        k_gemm_hidden<<<dim3(B_/BM, E_/BN), 256, 0, stream>>>(in, Wh, bh, outx);
        float* tmp = (float*)in;
        in = outx;
        outx = tmp;
    }

    // 3) logit-difference GEMM against theta
    k_theta_gemm<<<dim3(B_/BM, (NN + BN - 1)/BN), 256, 0, stream>>>(in, thW, thb, sm);

    // 4) leaf products
    k_leaf<<<(B_ * L_) / 256, 256, 0, stream>>>(sm, out);
}

// Round 2
// 194.695 us; speedup vs baseline: 1.4107x; 1.4107x over previous
//
#include <hip/hip_runtime.h>
#include <math.h>

#define B_  1024
#define S_  50
#define E_  512
#define L_  1024
#define D_  10
#define NN  1023   // N_NODES
#define LN_EPS 1e-5f
#define PROWS 513  // 512 matrix rows + 1 bias row

// ---------------- Kernel A: embedding gather + mean + LayerNorm ----------------
// One block per batch row b. 256 threads, each owns columns 2t, 2t+1 (float2).
__global__ __launch_bounds__(256) void k_embed_ln(const int* __restrict__ ids,
                                                  const float* __restrict__ emb,
                                                  float* __restrict__ x) {
    const int b = blockIdx.x;
    const int t = threadIdx.x;
    float a0 = 0.f, a1 = 0.f;
    const int* idr = ids + b * S_;
    #pragma unroll 5
    for (int s = 0; s < S_; ++s) {
        const float2 v = *reinterpret_cast<const float2*>(emb + (long)idr[s] * E_ + 2 * t);
        a0 += v.x;
        a1 += v.y;
    }
    a0 *= (1.f / S_);
    a1 *= (1.f / S_);

    __shared__ float red[256];
    red[t] = a0 + a1;
    __syncthreads();
    for (int off = 128; off > 0; off >>= 1) {
        if (t < off) red[t] += red[t + off];
        __syncthreads();
    }
    const float mean = red[0] * (1.f / E_);
    __syncthreads();
    const float d0 = a0 - mean, d1 = a1 - mean;
    red[t] = d0 * d0 + d1 * d1;
    __syncthreads();
    for (int off = 128; off > 0; off >>= 1) {
        if (t < off) red[t] += red[t + off];
        __syncthreads();
    }
    const float var = red[0] * (1.f / E_);
    const float inv = 1.f / sqrtf(var + LN_EPS);
    float2 o; o.x = d0 * inv; o.y = d1 * inv;
    *reinterpret_cast<float2*>(x + b * E_ + 2 * t) = o;
}

// ---------------- Kernel P: pack [W; b] into a 513x512 affine block ----------------
__global__ __launch_bounds__(256) void k_pack(const float* __restrict__ W,
                                              const float* __restrict__ b,
                                              float* __restrict__ P) {
    const int i = blockIdx.x * 256 + threadIdx.x;
    if (i < PROWS * E_) {
        P[i] = (i < E_ * E_) ? W[i] : b[i - E_ * E_];
    }
}

#define BM 64
#define BN 32
#define BK 32

// ---------------- Kernel F: affine compose C = A ∘then B ----------------
// A, B, C are 513x512 blocks [M; c]. Computes C.M = A.M @ B.M,
// C.c = A.c @ B.M + B.c  (i.e. f_C = f_B ∘ f_A, apply A first).
// Implemented as (513x512) @ B.M with "+B.c" epilogue on row 512.
__global__ __launch_bounds__(256) void k_affine(const float* __restrict__ A,
                                                const float* __restrict__ Bp,
                                                float* __restrict__ C) {
    __shared__ float As[BM][BK + 1];
    __shared__ float Ws[BK][BN + 1];
    const int tid = threadIdx.x;
    const int tx = tid & 15;
    const int ty = tid >> 4;
    const int row0 = blockIdx.x * BM;
    const int col0 = blockIdx.y * BN;
    float acc[4][2] = {};
    for (int kt = 0; kt < E_; kt += BK) {
        #pragma unroll
        for (int i = 0; i < 2; ++i) {
            const int idx = tid + i * 256;
            const int r  = idx >> 3;
            const int c4 = (idx & 7) << 2;
            int gr = row0 + r;
            if (gr > E_) gr = E_;                 // clamp; extra rows unused
            const float4 v = *reinterpret_cast<const float4*>(&A[(long)gr * E_ + kt + c4]);
            As[r][c4+0] = v.x; As[r][c4+1] = v.y; As[r][c4+2] = v.z; As[r][c4+3] = v.w;
        }
        {
            const int r  = tid >> 3;
            const int c4 = (tid & 7) << 2;
            const float4 v = *reinterpret_cast<const float4*>(&Bp[(long)(kt + r) * E_ + col0 + c4]);
            Ws[r][c4+0] = v.x; Ws[r][c4+1] = v.y; Ws[r][c4+2] = v.z; Ws[r][c4+3] = v.w;
        }
        __syncthreads();
        #pragma unroll
        for (int k = 0; k < BK; ++k) {
            const float a0 = As[ty*4+0][k], a1 = As[ty*4+1][k];
            const float a2 = As[ty*4+2][k], a3 = As[ty*4+3][k];
            const float w0 = Ws[k][tx*2+0], w1 = Ws[k][tx*2+1];
            acc[0][0] += a0*w0; acc[0][1] += a0*w1;
            acc[1][0] += a1*w0; acc[1][1] += a1*w1;
            acc[2][0] += a2*w0; acc[2][1] += a2*w1;
            acc[3][0] += a3*w0; acc[3][1] += a3*w1;
        }
        __syncthreads();
    }
    #pragma unroll
    for (int m = 0; m < 4; ++m) {
        const int r = row0 + ty*4 + m;
        if (r < PROWS) {
            #pragma unroll
            for (int n = 0; n < 2; ++n) {
                const int c = col0 + tx*2 + n;
                float v = acc[m][n];
                if (r == E_) v += Bp[(long)E_ * E_ + c];   // += c_B on the bias row
                C[(long)r * E_ + c] = v;
            }
        }
    }
}

// ---------------- Kernel B: f32 GEMM  C[1024,512] = A[1024,512] @ W[512,512] + bias ----------------
__global__ __launch_bounds__(256) void k_gemm_hidden(const float* __restrict__ A,
                                                     const float* __restrict__ W,
                                                     const float* __restrict__ bias,
                                                     float* __restrict__ C) {
    __shared__ float As[BM][BK + 1];
    __shared__ float Ws[BK][BN + 1];
    const int tid = threadIdx.x;
    const int tx = tid & 15;
    const int ty = tid >> 4;
    const int row0 = blockIdx.x * BM;
    const int col0 = blockIdx.y * BN;
    float acc[4][2] = {};
    for (int kt = 0; kt < E_; kt += BK) {
        #pragma unroll
        for (int i = 0; i < 2; ++i) {
            const int idx = tid + i * 256;
            const int r  = idx >> 3;
            const int c4 = (idx & 7) << 2;
            const float4 v = *reinterpret_cast<const float4*>(&A[(row0 + r) * E_ + kt + c4]);
            As[r][c4+0] = v.x; As[r][c4+1] = v.y; As[r][c4+2] = v.z; As[r][c4+3] = v.w;
        }
        {
            const int r  = tid >> 3;
            const int c4 = (tid & 7) << 2;
            const float4 v = *reinterpret_cast<const float4*>(&W[(kt + r) * E_ + col0 + c4]);
            Ws[r][c4+0] = v.x; Ws[r][c4+1] = v.y; Ws[r][c4+2] = v.z; Ws[r][c4+3] = v.w;
        }
        __syncthreads();
        #pragma unroll
        for (int k = 0; k < BK; ++k) {
            const float a0 = As[ty*4+0][k], a1 = As[ty*4+1][k];
            const float a2 = As[ty*4+2][k], a3 = As[ty*4+3][k];
            const float w0 = Ws[k][tx*2+0], w1 = Ws[k][tx*2+1];
            acc[0][0] += a0*w0; acc[0][1] += a0*w1;
            acc[1][0] += a1*w0; acc[1][1] += a1*w1;
            acc[2][0] += a2*w0; acc[2][1] += a2*w1;
            acc[3][0] += a3*w0; acc[3][1] += a3*w1;
        }
        __syncthreads();
    }
    #pragma unroll
    for (int m = 0; m < 4; ++m) {
        const int r = row0 + ty*4 + m;
        #pragma unroll
        for (int n = 0; n < 2; ++n) {
            const int c = col0 + tx*2 + n;
            C[r * E_ + c] = acc[m][n] + bias[c];
        }
    }
}

// ---------------- Kernel C: s[b,n] = x[b,:] . (thW[n,:,1]-thW[n,:,0]) + (thb[n,1]-thb[n,0]) ----------------
__global__ __launch_bounds__(256) void k_theta_gemm(const float* __restrict__ X,
                                                    const float* __restrict__ thW,
                                                    const float* __restrict__ thb,
                                                    float* __restrict__ Sm) {
    __shared__ float As[BM][BK + 1];
    __shared__ float Ds[BN][BK + 1];
    const int tid = threadIdx.x;
    const int tx = tid & 15;
    const int ty = tid >> 4;
    const int row0 = blockIdx.x * BM;
    const int n0   = blockIdx.y * BN;
    float acc[4][2] = {};
    for (int kt = 0; kt < E_; kt += BK) {
        #pragma unroll
        for (int i = 0; i < 2; ++i) {
            const int idx = tid + i * 256;
            const int r  = idx >> 3;
            const int c4 = (idx & 7) << 2;
            const float4 v = *reinterpret_cast<const float4*>(&X[(row0 + r) * E_ + kt + c4]);
            As[r][c4+0] = v.x; As[r][c4+1] = v.y; As[r][c4+2] = v.z; As[r][c4+3] = v.w;
        }
        #pragma unroll
        for (int j = 0; j < 4; ++j) {
            const int idx = tid + j * 256;
            const int nl = idx >> 5;
            const int el = idx & 31;
            const int n  = n0 + nl;
            float dv = 0.f;
            if (n < NN) {
                const float2 v = *reinterpret_cast<const float2*>(&thW[((long)n * E_ + kt + el) * 2]);
                dv = v.y - v.x;
            }
            Ds[nl][el] = dv;
        }
        __syncthreads();
        #pragma unroll
        for (int k = 0; k < BK; ++k) {
            const float a0 = As[ty*4+0][k], a1 = As[ty*4+1][k];
            const float a2 = As[ty*4+2][k], a3 = As[ty*4+3][k];
            const float w0 = Ds[tx*2+0][k], w1 = Ds[tx*2+1][k];
            acc[0][0] += a0*w0; acc[0][1] += a0*w1;
            acc[1][0] += a1*w0; acc[1][1] += a1*w1;
            acc[2][0] += a2*w0; acc[2][1] += a2*w1;
            acc[3][0] += a3*w0; acc[3][1] += a3*w1;
        }
        __syncthreads();
    }
    #pragma unroll
    for (int m = 0; m < 4; ++m) {
        const int r = row0 + ty*4 + m;
        #pragma unroll
        for (int n = 0; n < 2; ++n) {
            const int c = n0 + tx*2 + n;
            if (c < NN) {
                Sm[(long)r * NN + c] = acc[m][n] + (thb[c*2+1] - thb[c*2+0]);
            }
        }
    }
}

// ---------------- Kernel D: per-leaf product of path sigmoids ----------------
__global__ __launch_bounds__(256) void k_leaf(const float* __restrict__ Sm,
                                              float* __restrict__ out) {
    const int idx = blockIdx.x * 256 + threadIdx.x;
    const int b = idx >> 10;
    const int l = idx & (L_ - 1);
    const float* srow = Sm + (long)b * NN;
    float prod = 1.f;
    #pragma unroll
    for (int t = 0; t < D_; ++t) {
        const int node = (1 << t) - 1 + (l >> (D_ - t));
        const int bit  = (l >> (D_ - 1 - t)) & 1;
        float z = srow[node];
        z = bit ? z : -z;
        prod *= 1.f / (1.f + expf(-z));
    }
    out[idx] = prod;
}

extern "C" void kernel_launch(void* const* d_in, const int* in_sizes, int n_in,
                              void* d_out, int out_size, void* d_ws, size_t ws_size,
                              hipStream_t stream) {
    const int*   ids = (const int*)d_in[0];
    const float* emb = (const float*)d_in[1];
    const float* Wh  = (const float*)d_in[2];
    const float* bh  = (const float*)d_in[3];
    const float* thW = (const float*)d_in[4];
    const float* thb = (const float*)d_in[5];
    float* out = (float*)d_out;

    char* ws = (char*)d_ws;
    float* xa = (float*)(ws);                      // 2 MB
    float* xb = (float*)(ws + (2u << 20));         // 2 MB
    float* sm = (float*)(ws + (4u << 20));         // ~4.19 MB
    const size_t PSTRIDE = 0x140000;               // 1.25 MB per 513x512 slot
    float* Q0 = (float*)(ws + (9u << 20));                 // P1 = [W; b]
    float* Q1 = (float*)(ws + (9u << 20) + PSTRIDE);       // P2
    float* Q2 = (float*)(ws + (9u << 20) + 2 * PSTRIDE);   // P4, then P10
    float* Q3 = (float*)(ws + (9u << 20) + 3 * PSTRIDE);   // P8

    const dim3 agrid((PROWS + BM - 1) / BM, E_ / BN);      // 9 x 16

    // Affine power chain: f^10 = f^2 ∘ f^8
    k_pack<<<(PROWS * E_ + 255) / 256, 256, 0, stream>>>(Wh, bh, Q0);
    k_affine<<<agrid, 256, 0, stream>>>(Q0, Q0, Q1);       // P2
    k_affine<<<agrid, 256, 0, stream>>>(Q1, Q1, Q2);       // P4
    k_affine<<<agrid, 256, 0, stream>>>(Q2, Q2, Q3);       // P8
    k_affine<<<agrid, 256, 0, stream>>>(Q3, Q1, Q2);       // P10 = P2 ∘ P8 (overwrites P4)

    // Embedding mean + LN
    k_embed_ln<<<B_, 256, 0, stream>>>(ids, emb, xa);

    // Single batch GEMM: x10 = x @ M10 + c10
    k_gemm_hidden<<<dim3(B_/BM, E_/BN), 256, 0, stream>>>(xa, Q2, Q2 + (long)E_ * E_, xb);

    // Logit-difference GEMM against theta
    k_theta_gemm<<<dim3(B_/BM, (NN + BN - 1)/BN), 256, 0, stream>>>(xb, thW, thb, sm);

    // Leaf products
    k_leaf<<<(B_ * L_) / 256, 256, 0, stream>>>(sm, out);
}

// Round 3
// 182.501 us; speedup vs baseline: 1.5050x; 1.0668x over previous
//
#include <hip/hip_runtime.h>
#include <math.h>

#define B_  1024
#define S_  50
#define E_  512
#define L_  1024
#define D_  10
#define NN  1023   // N_NODES
#define LN_EPS 1e-5f
#define PROWS 513  // 512 matrix rows + 1 bias row

typedef short short8 __attribute__((ext_vector_type(8)));
typedef float f32x4  __attribute__((ext_vector_type(4)));

union PackU { unsigned int u[4]; short8 s; };

// Split 8 f32 into bf16 hi (truncation; lo captures the remainder EXACTLY)
// and bf16 lo (RNE via v_cvt_pk_bf16_f32). Dropping lo*lo in the GEMM gives
// ~2^-16 relative error per dot product — far under the 1.5e-3 threshold.
__device__ inline void split8(const float r[8], short8& hi, short8& lo) {
    PackU H, L;
    #pragma unroll
    for (int q = 0; q < 4; ++q) {
        const unsigned int u0 = __float_as_uint(r[2*q+0]);
        const unsigned int u1 = __float_as_uint(r[2*q+1]);
        H.u[q] = (u0 >> 16) | (u1 & 0xFFFF0000u);
        const float h0 = __uint_as_float(u0 & 0xFFFF0000u);
        const float h1 = __uint_as_float(u1 & 0xFFFF0000u);
        const float l0 = r[2*q+0] - h0;
        const float l1 = r[2*q+1] - h1;
        unsigned int p;
        asm("v_cvt_pk_bf16_f32 %0, %1, %2" : "=v"(p) : "v"(l0), "v"(l1));
        L.u[q] = p;
    }
    hi = H.s; lo = L.s;
}

// ---------------- Kernel A: embedding gather + mean + LayerNorm ----------------
__global__ __launch_bounds__(256) void k_embed_ln(const int* __restrict__ ids,
                                                  const float* __restrict__ emb,
                                                  float* __restrict__ x) {
    const int b = blockIdx.x;
    const int t = threadIdx.x;
    float a0 = 0.f, a1 = 0.f;
    const int* idr = ids + b * S_;
    #pragma unroll 5
    for (int s = 0; s < S_; ++s) {
        const float2 v = *reinterpret_cast<const float2*>(emb + (long)idr[s] * E_ + 2 * t);
        a0 += v.x;
        a1 += v.y;
    }
    a0 *= (1.f / S_);
    a1 *= (1.f / S_);

    __shared__ float red[256];
    red[t] = a0 + a1;
    __syncthreads();
    for (int off = 128; off > 0; off >>= 1) {
        if (t < off) red[t] += red[t + off];
        __syncthreads();
    }
    const float mean = red[0] * (1.f / E_);
    __syncthreads();
    const float d0 = a0 - mean, d1 = a1 - mean;
    red[t] = d0 * d0 + d1 * d1;
    __syncthreads();
    for (int off = 128; off > 0; off >>= 1) {
        if (t < off) red[t] += red[t + off];
        __syncthreads();
    }
    const float var = red[0] * (1.f / E_);
    const float inv = 1.f / sqrtf(var + LN_EPS);
    float2 o; o.x = d0 * inv; o.y = d1 * inv;
    *reinterpret_cast<float2*>(x + b * E_ + 2 * t) = o;
}

// ---------------- Kernel P: pack [W; b] into a 513x512 affine block ----------------
__global__ __launch_bounds__(256) void k_pack(const float* __restrict__ W,
                                              const float* __restrict__ b,
                                              float* __restrict__ P) {
    const int i = blockIdx.x * 256 + threadIdx.x;
    if (i < PROWS * E_) {
        P[i] = (i < E_ * E_) ? W[i] : b[i - E_ * E_];
    }
}

#define BM 64
#define BN 32
#define BK 32

// ---------------- Kernel F: affine compose (f32), optional transposed matrix store ----
__global__ __launch_bounds__(256) void k_affine(const float* __restrict__ A,
                                                const float* __restrict__ Bp,
                                                float* __restrict__ C,
                                                float* __restrict__ Ct) {
    __shared__ float As[BM][BK + 1];
    __shared__ float Ws[BK][BN + 1];
    const int tid = threadIdx.x;
    const int tx = tid & 15;
    const int ty = tid >> 4;
    const int row0 = blockIdx.x * BM;
    const int col0 = blockIdx.y * BN;
    float acc[4][2] = {};
    for (int kt = 0; kt < E_; kt += BK) {
        #pragma unroll
        for (int i = 0; i < 2; ++i) {
            const int idx = tid + i * 256;
            const int r  = idx >> 3;
            const int c4 = (idx & 7) << 2;
            int gr = row0 + r;
            if (gr > E_) gr = E_;
            const float4 v = *reinterpret_cast<const float4*>(&A[(long)gr * E_ + kt + c4]);
            As[r][c4+0] = v.x; As[r][c4+1] = v.y; As[r][c4+2] = v.z; As[r][c4+3] = v.w;
        }
        {
            const int r  = tid >> 3;
            const int c4 = (tid & 7) << 2;
            const float4 v = *reinterpret_cast<const float4*>(&Bp[(long)(kt + r) * E_ + col0 + c4]);
            Ws[r][c4+0] = v.x; Ws[r][c4+1] = v.y; Ws[r][c4+2] = v.z; Ws[r][c4+3] = v.w;
        }
        __syncthreads();
        #pragma unroll
        for (int k = 0; k < BK; ++k) {
            const float a0 = As[ty*4+0][k], a1 = As[ty*4+1][k];
            const float a2 = As[ty*4+2][k], a3 = As[ty*4+3][k];
            const float w0 = Ws[k][tx*2+0], w1 = Ws[k][tx*2+1];
            acc[0][0] += a0*w0; acc[0][1] += a0*w1;
            acc[1][0] += a1*w0; acc[1][1] += a1*w1;
            acc[2][0] += a2*w0; acc[2][1] += a2*w1;
            acc[3][0] += a3*w0; acc[3][1] += a3*w1;
        }
        __syncthreads();
    }
    #pragma unroll
    for (int m = 0; m < 4; ++m) {
        const int r = row0 + ty*4 + m;
        if (r < PROWS) {
            #pragma unroll
            for (int n = 0; n < 2; ++n) {
                const int c = col0 + tx*2 + n;
                float v = acc[m][n];
                if (r == E_) v += Bp[(long)E_ * E_ + c];
                C[(long)r * E_ + c] = v;
                if (Ct != nullptr && r < E_) Ct[(long)c * E_ + r] = v;  // n-major copy
            }
        }
    }
}

// ---------------- Kernel M: split-bf16 MFMA GEMM (no LDS, wave-tile 32x32) ----------
// C[1024, N] = A[1024,512] @ B + bias, where B is consumed k-contiguously:
//   THETA=false: Bt[n][k] (n-major, 512x512), bias[n]
//   THETA=true : B[k][n] = thW[n][k][1]-thW[n][k][0], bias = thb[n][1]-thb[n][0]
template<bool THETA>
__global__ __launch_bounds__(256) void k_mfma_gemm(const float* __restrict__ A,
                                                   const float* __restrict__ Bsrc,
                                                   const float* __restrict__ bias,
                                                   float* __restrict__ C,
                                                   int ldc) {
    const int tid  = threadIdx.x;
    const int wid  = tid >> 6;
    const int lane = tid & 63;
    const int r_lo = lane & 15;
    const int kg   = lane >> 4;          // k-group 0..3 (8 consecutive k each)
    const int row_base = blockIdx.x * 64 + (wid >> 1) * 32;
    const int col_base = blockIdx.y * 64 + (wid & 1) * 32;

    f32x4 acc[2][2] = {};

    #pragma unroll 2
    for (int kt = 0; kt < E_; kt += 32) {
        const int ks = kt + kg * 8;
        short8 ah[2], al[2], bh[2], bl[2];
        // A fragments
        #pragma unroll
        for (int i = 0; i < 2; ++i) {
            const int row = row_base + i * 16 + r_lo;
            const float4 v0 = *reinterpret_cast<const float4*>(&A[row * E_ + ks]);
            const float4 v1 = *reinterpret_cast<const float4*>(&A[row * E_ + ks + 4]);
            const float r[8] = {v0.x, v0.y, v0.z, v0.w, v1.x, v1.y, v1.z, v1.w};
            split8(r, ah[i], al[i]);
        }
        // B fragments
        #pragma unroll
        for (int j = 0; j < 2; ++j) {
            int n = col_base + j * 16 + r_lo;
            if (THETA && n > NN - 1) n = NN - 1;
            float r[8];
            if (THETA) {
                const float* bp = Bsrc + (long)n * (2 * E_) + ks * 2;
                const float4 q0 = *reinterpret_cast<const float4*>(bp);
                const float4 q1 = *reinterpret_cast<const float4*>(bp + 4);
                const float4 q2 = *reinterpret_cast<const float4*>(bp + 8);
                const float4 q3 = *reinterpret_cast<const float4*>(bp + 12);
                r[0] = q0.y - q0.x; r[1] = q0.w - q0.z;
                r[2] = q1.y - q1.x; r[3] = q1.w - q1.z;
                r[4] = q2.y - q2.x; r[5] = q2.w - q2.z;
                r[6] = q3.y - q3.x; r[7] = q3.w - q3.z;
            } else {
                const float4 v0 = *reinterpret_cast<const float4*>(&Bsrc[n * E_ + ks]);
                const float4 v1 = *reinterpret_cast<const float4*>(&Bsrc[n * E_ + ks + 4]);
                r[0]=v0.x; r[1]=v0.y; r[2]=v0.z; r[3]=v0.w;
                r[4]=v1.x; r[5]=v1.y; r[6]=v1.z; r[7]=v1.w;
            }
            split8(r, bh[j], bl[j]);
        }
        // 3-term split product: hi*hi + hi*lo + lo*hi
        #pragma unroll
        for (int i = 0; i < 2; ++i)
            #pragma unroll
            for (int j = 0; j < 2; ++j) {
                acc[i][j] = __builtin_amdgcn_mfma_f32_16x16x32_bf16(ah[i], bh[j], acc[i][j], 0, 0, 0);
                acc[i][j] = __builtin_amdgcn_mfma_f32_16x16x32_bf16(ah[i], bl[j], acc[i][j], 0, 0, 0);
                acc[i][j] = __builtin_amdgcn_mfma_f32_16x16x32_bf16(al[i], bh[j], acc[i][j], 0, 0, 0);
            }
    }

    // Epilogue. C/D layout (m89-verified): col = lane&15, row = (lane>>4)*4 + reg.
    #pragma unroll
    for (int j = 0; j < 2; ++j) {
        const int col = col_base + j * 16 + r_lo;
        float bb;
        if (THETA) {
            const int cc = (col > NN - 1) ? (NN - 1) : col;
            bb = bias[2 * cc + 1] - bias[2 * cc + 0];
        } else {
            bb = bias[col];
        }
        #pragma unroll
        for (int i = 0; i < 2; ++i) {
            #pragma unroll
            for (int rr = 0; rr < 4; ++rr) {
                const int row = row_base + i * 16 + kg * 4 + rr;
                if (!THETA || col < NN) {
                    C[(long)row * ldc + col] = acc[i][j][rr] + bb;
                }
            }
        }
    }
}

// ---------------- Kernel D: tree cumulative-product of path sigmoids ----------------
// sig(-z) = 1 - sig(z): one expf per node (1023/row) instead of 10 per leaf (10240/row).
__global__ __launch_bounds__(256) void k_leaf_tree(const float* __restrict__ Sm,
                                                   float* __restrict__ out) {
    __shared__ float buf[2][L_];
    const int b = blockIdx.x;
    const int tid = threadIdx.x;
    const float* srow = Sm + b * NN;
    if (tid == 0) buf[0][0] = 1.f;
    __syncthreads();
    int cur = 0;
    for (int t = 0; t < D_; ++t) {
        const int cnt = 1 << t;
        const int base = cnt - 1;
        for (int j = tid; j < cnt; j += 256) {
            const float z = srow[base + j];
            const float s = 1.f / (1.f + __expf(-z));
            const float a = buf[cur][j];
            buf[cur ^ 1][2*j + 1] = a * s;
            buf[cur ^ 1][2*j + 0] = a - a * s;
        }
        __syncthreads();
        cur ^= 1;
    }
    reinterpret_cast<float4*>(out + b * L_)[tid] =
        reinterpret_cast<const float4*>(buf[cur])[tid];
}

extern "C" void kernel_launch(void* const* d_in, const int* in_sizes, int n_in,
                              void* d_out, int out_size, void* d_ws, size_t ws_size,
                              hipStream_t stream) {
    const int*   ids = (const int*)d_in[0];
    const float* emb = (const float*)d_in[1];
    const float* Wh  = (const float*)d_in[2];
    const float* bh  = (const float*)d_in[3];
    const float* thW = (const float*)d_in[4];
    const float* thb = (const float*)d_in[5];
    float* out = (float*)d_out;

    char* ws = (char*)d_ws;
    float* xa = (float*)(ws);                      // 2 MB
    float* xb = (float*)(ws + (2u << 20));         // 2 MB
    float* sm = (float*)(ws + (4u << 20));         // ~4.19 MB
    const size_t PSTRIDE = 0x140000;               // 1.25 MB per 513x512 slot
    float* Q0  = (float*)(ws + (9u << 20));
    float* Q1  = (float*)(ws + (9u << 20) + PSTRIDE);
    float* Q2  = (float*)(ws + (9u << 20) + 2 * PSTRIDE);   // P4, then P10
    float* Q3  = (float*)(ws + (9u << 20) + 3 * PSTRIDE);   // P8
    float* Q2t = (float*)(ws + (9u << 20) + 4 * PSTRIDE);   // M10 transposed (1 MB)

    const dim3 agrid((PROWS + BM - 1) / BM, E_ / BN);       // 9 x 16

    // Affine power chain: f^10 = f^8 then f^2
    k_pack<<<(PROWS * E_ + 255) / 256, 256, 0, stream>>>(Wh, bh, Q0);
    k_affine<<<agrid, 256, 0, stream>>>(Q0, Q0, Q1, nullptr);   // P2
    k_affine<<<agrid, 256, 0, stream>>>(Q1, Q1, Q2, nullptr);   // P4
    k_affine<<<agrid, 256, 0, stream>>>(Q2, Q2, Q3, nullptr);   // P8
    k_affine<<<agrid, 256, 0, stream>>>(Q3, Q1, Q2, Q2t);       // P10 (+ transposed matrix)

    // Embedding mean + LN
    k_embed_ln<<<B_, 256, 0, stream>>>(ids, emb, xa);

    // x10 = x @ M10 + c10   (split-bf16 MFMA)
    k_mfma_gemm<false><<<dim3(B_/64, E_/64), 256, 0, stream>>>(xa, Q2t, Q2 + (long)E_ * E_, xb, E_);

    // s[b,n] = x10 . dtheta_n + dthb_n   (split-bf16 MFMA)
    k_mfma_gemm<true><<<dim3(B_/64, (NN + 63)/64), 256, 0, stream>>>(xb, thW, thb, sm, NN);

    // Leaf products via tree
    k_leaf_tree<<<B_, 256, 0, stream>>>(sm, out);
}